// Round 3
// baseline (399.116 us; speedup 1.0000x reference)
//
#include <hip/hip_runtime.h>
#include <math.h>

// VectorQuantizer: in [32,64,64,64] fp32 NCHW (C=D=64), w [512,64] fp32.
// GEMM-shaped: X[131072x64] . W^T[64x512] + row argmin. fp32 VALU floor ~55 us.
// Register-blocked: block = 64 queries x 512 codes (4 passes of 128),
// 256 thr = 16 tx (8 codes) x 16 ty (4 queries), 4x8 acc tile per thread.
#define VQ_D 64
#define VQ_K 512
#define VQ_NQ 131072
#define VQ_TOTAL 8388608
#define QT 64      // queries per block
#define KT 128     // codes per pass
#define NPASS 4    // VQ_K / KT

__global__ __launch_bounds__(256) void vq_main(const float* __restrict__ in,
                                               const float* __restrict__ w,
                                               float* __restrict__ out) {
    __shared__ __align__(16) float x_lds[VQ_D * QT];   // [d][q]  16 KB
    __shared__ __align__(16) float w_lds[VQ_D * KT];   // [d][k]  32 KB (transposed)
    __shared__ float wn_lds[KT];
    __shared__ float xnorm_lds[QT];
    __shared__ int   bidx_lds[QT];
    __shared__ double loss_part[16];

    const int tid = threadIdx.x;
    const int tx = tid & 15;    // code group: codes 8*tx..8*tx+7 of each pass
    const int ty = tid >> 4;    // query group: queries 4*ty..4*ty+3
    const int n0 = blockIdx.x * QT;
    const int b  = n0 >> 12;
    const int hw0 = n0 & 4095;
    const float* xbase = in + (b << 18) + hw0;
    float* obase = out + (b << 18) + hw0;

    // ---- stage x tile [d][q]: coalesced global (64 consecutive floats per d) ----
    {
        const int q = tid & 63, db = tid >> 6;
#pragma unroll
        for (int i = 0; i < 16; ++i) {
            const int d = 4 * i + db;
            x_lds[d * QT + q] = xbase[(d << 12) + q];
        }
    }
    __syncthreads();

    // ---- query norms (wave 0; 2 lanes/bank = free) ----
    if (tid < QT) {
        float s = 0.f;
#pragma unroll 8
        for (int d = 0; d < VQ_D; ++d) {
            float v = x_lds[d * QT + tid];
            s = fmaf(v, v, s);
        }
        xnorm_lds[tid] = s;
    }

    float best[4], secnd[4];
    int bI[4], sI[4];
#pragma unroll
    for (int j = 0; j < 4; ++j) { best[j] = 3.4e38f; secnd[j] = 3.4e38f; bI[j] = 0; sI[j] = 0; }

    const float4* w4 = (const float4*)w;

    for (int pass = 0; pass < NPASS; ++pass) {
        __syncthreads();   // previous pass's w_lds/wn_lds fully consumed
        // ---- stage w tile transposed [d][k] + code norms ----
        {
            const int kk = tid >> 1, hf = tid & 1;   // code kk, d-half hf
            const float4* wrow = w4 + (pass * KT + kk) * 16 + hf * 8;
            float pn = 0.f;
#pragma unroll
            for (int i = 0; i < 8; ++i) {
                float4 v = wrow[i];
                pn = fmaf(v.x, v.x, pn); pn = fmaf(v.y, v.y, pn);
                pn = fmaf(v.z, v.z, pn); pn = fmaf(v.w, v.w, pn);
                const int d0 = hf * 32 + 4 * i;
                w_lds[(d0 + 0) * KT + kk] = v.x;   // lanes: consecutive kk -> 2-way max
                w_lds[(d0 + 1) * KT + kk] = v.y;
                w_lds[(d0 + 2) * KT + kk] = v.z;
                w_lds[(d0 + 3) * KT + kk] = v.w;
            }
            pn += __shfl_xor(pn, 1, 64);
            if (hf == 0) wn_lds[kk] = pn;
        }
        __syncthreads();

        float acc[4][8];
#pragma unroll
        for (int j = 0; j < 4; ++j)
#pragma unroll
            for (int k = 0; k < 8; ++k) acc[j][k] = 0.f;

        const float* xq = x_lds + 4 * ty;
        const float* wk = w_lds + 8 * tx;
#pragma unroll 4
        for (int d = 0; d < VQ_D; ++d) {
            float4 xv = *(const float4*)(xq + d * QT);      // 4 distinct/wave: ~free
            float4 wa = *(const float4*)(wk + d * KT);      // 16 distinct/wave
            float4 wb = *(const float4*)(wk + d * KT + 4);
            float xs0 = xv.x, xs1 = xv.y, xs2 = xv.z, xs3 = xv.w;
#define VQ_FMA8(J, XS) \
            acc[J][0] = fmaf(XS, wa.x, acc[J][0]); acc[J][1] = fmaf(XS, wa.y, acc[J][1]); \
            acc[J][2] = fmaf(XS, wa.z, acc[J][2]); acc[J][3] = fmaf(XS, wa.w, acc[J][3]); \
            acc[J][4] = fmaf(XS, wb.x, acc[J][4]); acc[J][5] = fmaf(XS, wb.y, acc[J][5]); \
            acc[J][6] = fmaf(XS, wb.z, acc[J][6]); acc[J][7] = fmaf(XS, wb.w, acc[J][7]);
            VQ_FMA8(0, xs0) VQ_FMA8(1, xs1) VQ_FMA8(2, xs2) VQ_FMA8(3, xs3)
#undef VQ_FMA8
        }

        // ---- fold into per-thread best/second (ascending k -> first-index ties) ----
        const int kg0 = pass * KT + 8 * tx;
#pragma unroll
        for (int j = 0; j < 4; ++j)
#pragma unroll
            for (int k = 0; k < 8; ++k) {
                float dist = fmaf(-2.f, acc[j][k], wn_lds[8 * tx + k]);
                const int kg = kg0 + k;
                bool lt  = dist < best[j];
                bool lt2 = (!lt) && (dist < secnd[j]);
                secnd[j] = lt ? best[j] : (lt2 ? dist : secnd[j]);
                sI[j]    = lt ? bI[j]   : (lt2 ? kg   : sI[j]);
                best[j]  = lt ? dist    : best[j];
                bI[j]    = lt ? kg      : bI[j];
            }
    }

    // ---- merge across the 16 tx threads (same ty share queries); disjoint code sets ----
#pragma unroll
    for (int off = 1; off < 16; off <<= 1) {
#pragma unroll
        for (int j = 0; j < 4; ++j) {
            float ob = __shfl_xor(best[j], off, 64);
            float os = __shfl_xor(secnd[j], off, 64);
            int   oi = __shfl_xor(bI[j], off, 64);
            int   oc = __shfl_xor(sI[j], off, 64);
            bool oWins = (ob < best[j]) || (ob == best[j] && oi < bI[j]);
            float nb  = oWins ? ob      : best[j];
            int   ni  = oWins ? oi      : bI[j];
            float c1  = oWins ? best[j] : ob;      // loser's best
            int   ci1 = oWins ? bI[j]   : oi;
            float c2  = oWins ? os      : secnd[j];// winner's second
            int   ci2 = oWins ? oc      : sI[j];
            bool c1w = (c1 < c2) || (c1 == c2 && ci1 < ci2);
            secnd[j] = c1w ? c1 : c2;
            sI[j]    = c1w ? ci1 : ci2;
            best[j] = nb; bI[j] = ni;
        }
    }

    // ---- near-tie fp64 refinement + loss partials (tx==0 lanes only) ----
    if (tx == 0) {
        double dsum = 0.0;
        for (int j = 0; j < 4; ++j) {
            const int q = 4 * ty + j;
            double chosen = (double)best[j];
            int cbi = bI[j];
            if (secnd[j] - best[j] < 4e-3f) {
                const float* wb = w + bI[j] * VQ_D;
                const float* ws2 = w + sI[j] * VQ_D;
                double nb = 0.0, dotb = 0.0, ns = 0.0, dots = 0.0;
                for (int d = 0; d < VQ_D; ++d) {
                    double xv = (double)x_lds[d * QT + q];
                    double wbv = (double)wb[d], wsv = (double)ws2[d];
                    nb = fma(wbv, wbv, nb); dotb = fma(xv, wbv, dotb);
                    ns = fma(wsv, wsv, ns); dots = fma(xv, wsv, dots);
                }
                double db = nb - 2.0 * dotb, ds = ns - 2.0 * dots;
                if (ds < db || (ds == db && sI[j] < bI[j])) { cbi = sI[j]; chosen = ds; }
                else chosen = db;
            }
            bidx_lds[q] = cbi;
            dsum += (double)xnorm_lds[q] + chosen;   // ||x-e||^2 = xnorm + (wn - 2 dot)
        }
        loss_part[ty] = dsum;
    }
    __syncthreads();

    // ---- cooperative output write: coalesced 64-float rows per d ----
    {
        const int q = tid & 63, db = tid >> 6;
        const float* wr = w + bidx_lds[q] * VQ_D;   // gather, L2-hot 128 KB table
#pragma unroll
        for (int i = 0; i < 16; ++i) {
            const int d = 4 * i + db;
            obase[(d << 12) + q] = wr[d];
        }
    }
    if (tid == 0) {
        double t = 0.0;
#pragma unroll
        for (int i = 0; i < 16; ++i) t += loss_part[i];
        atomicAdd(out + VQ_TOTAL, (float)(t * (1.0 / (double)VQ_TOTAL)));
    }
}

extern "C" void kernel_launch(void* const* d_in, const int* in_sizes, int n_in,
                              void* d_out, int out_size, void* d_ws, size_t ws_size,
                              hipStream_t stream) {
    const float* in = (const float*)d_in[0];
    const float* w  = (const float*)d_in[1];
    float* out = (float*)d_out;

    hipMemsetAsync(out + VQ_TOTAL, 0, sizeof(float), stream);
    vq_main<<<VQ_NQ / QT, 256, 0, stream>>>(in, w, out);
}

// Round 4
// 374.291 us; speedup vs baseline: 1.0663x; 1.0663x over previous
//
#include <hip/hip_runtime.h>
#include <math.h>

// VectorQuantizer: in [32,64,64,64] fp32 NCHW (C=D=64), w [512,64] fp32.
// 1 query per thread, x[64] PINNED in VGPRs (asm barrier defeats compiler
// rematerialization -- R1/R2 showed VGPR=56..68 i.e. x was reloaded from
// global inside the K loop). w streamed through double-buffered LDS chunks,
// read wave-uniform -> broadcast, 0 bank conflicts (R2 measured 0).
#define VQ_D 64
#define VQ_K 512
#define VQ_NQ 131072
#define VQ_TOTAL 8388608
#define CHUNK 64           // codes per LDS chunk (16 KB)
#define NCHUNK 8

__global__ __launch_bounds__(256) void vq_main(const float* __restrict__ in,
                                               const float* __restrict__ w,
                                               float* __restrict__ out) {
    __shared__ __align__(16) float wbuf[2][CHUNK * VQ_D];  // 2 x 16 KB
    __shared__ float wn[VQ_K];                             // 2 KB code norms

    const int tid = threadIdx.x;
    const int n  = blockIdx.x * 256 + tid;
    const int b  = n >> 12;
    const int hw = n & 4095;
    const float* xp = in + (b << 18) + hw;    // NCHW: stride 4096 floats per d

    // ---- codebook norms (one-time, coalesced) ----
    for (int k = tid; k < VQ_K; k += 256) {
        const float4* wr = (const float4*)(w + k * VQ_D);
        float s0 = 0.f, s1 = 0.f, s2 = 0.f, s3 = 0.f;
#pragma unroll
        for (int i = 0; i < 16; ++i) {
            float4 v = wr[i];
            s0 = fmaf(v.x, v.x, s0); s1 = fmaf(v.y, v.y, s1);
            s2 = fmaf(v.z, v.z, s2); s3 = fmaf(v.w, v.w, s3);
        }
        wn[k] = (s0 + s1) + (s2 + s3);
    }

    // ---- query vector -> registers, then PIN so it stays there ----
    float x[VQ_D];
#pragma unroll
    for (int d = 0; d < VQ_D; ++d) x[d] = xp[d << 12];
#pragma unroll
    for (int d = 0; d < VQ_D; ++d) asm volatile("" : "+v"(x[d]));

    float xnorm = 0.f;
#pragma unroll
    for (int d = 0; d < VQ_D; ++d) xnorm = fmaf(x[d], x[d], xnorm);

    const float4* w4 = (const float4*)w;   // 8192 float4 (128 KB, L2-hot)

    // register prefetch of chunk 0 (1024 float4 across 256 threads)
    float4 st0 = w4[tid], st1 = w4[tid + 256], st2 = w4[tid + 512], st3 = w4[tid + 768];

    float best = 3.4e38f, second = 3.4e38f;
    int bidx = 0, sidx = 0;

    for (int c = 0; c < NCHUNK; ++c) {
        float4* dst = (float4*)wbuf[c & 1];
        dst[tid]       = st0;
        dst[tid + 256] = st1;
        dst[tid + 512] = st2;
        dst[tid + 768] = st3;
        __syncthreads();
        if (c + 1 < NCHUNK) {   // prefetch next chunk during this chunk's compute
            const float4* src = w4 + (c + 1) * 1024;
            st0 = src[tid]; st1 = src[tid + 256]; st2 = src[tid + 512]; st3 = src[tid + 768];
        }

        const float* wl = wbuf[c & 1];
        const int k0 = c * CHUNK;
#pragma unroll 2
        for (int j = 0; j < CHUNK; ++j) {
            const float* wk = wl + j * VQ_D;   // wave-uniform -> LDS broadcast, no conflicts
            float d0 = 0.f, d1 = 0.f, d2 = 0.f, d3 = 0.f;
#pragma unroll
            for (int d = 0; d < VQ_D; d += 4) {
                d0 = fmaf(x[d + 0], wk[d + 0], d0);
                d1 = fmaf(x[d + 1], wk[d + 1], d1);
                d2 = fmaf(x[d + 2], wk[d + 2], d2);
                d3 = fmaf(x[d + 3], wk[d + 3], d3);
            }
            const int k = k0 + j;
            float dist = fmaf(-2.f, (d0 + d1) + (d2 + d3), wn[k]);
            bool lt  = dist < best;
            bool lt2 = (!lt) && (dist < second);
            second = lt ? best : (lt2 ? dist : second);
            sidx   = lt ? bidx : (lt2 ? k    : sidx);
            best   = lt ? dist : best;
            bidx   = lt ? k    : bidx;
        }
        // one barrier per chunk: next iteration's writes go to the other buffer,
        // and a wave can only reach chunk c+2's writes after everyone passed
        // c+1's barrier (i.e. finished reading buf[c&1]).
    }

    // ---- near-tie refinement in fp64 (rare; argmin matches exact ordering) ----
    double chosen = (double)best;
    if (second - best < 4e-3f) {
        const float* wb  = w + bidx * VQ_D;
        const float* ws2 = w + sidx * VQ_D;
        double nb = 0.0, dotb = 0.0, ns = 0.0, dots = 0.0;
        for (int d = 0; d < VQ_D; ++d) {
            double xv = (double)x[d];
            double wbv = (double)wb[d], wsv = (double)ws2[d];
            nb = fma(wbv, wbv, nb); dotb = fma(xv, wbv, dotb);
            ns = fma(wsv, wsv, ns); dots = fma(xv, wsv, dots);
        }
        double db = nb - 2.0 * dotb, ds = ns - 2.0 * dots;
        if (ds < db || (ds == db && sidx < bidx)) { bidx = sidx; chosen = ds; }
        else                                      { chosen = db; }
    }

    // ---- gather chosen code -> NCHW output (coalesced across lanes per d) ----
    {
        const float4* wrow = (const float4*)(w + bidx * VQ_D);
        float* op = out + (b << 18) + hw;
#pragma unroll
        for (int i = 0; i < 16; ++i) {
            float4 v = wrow[i];
            op[(4 * i + 0) << 12] = v.x;
            op[(4 * i + 1) << 12] = v.y;
            op[(4 * i + 2) << 12] = v.z;
            op[(4 * i + 3) << 12] = v.w;
        }
    }

    // ---- loss: ||x-e||^2 = xnorm + (wnorm - 2 dot); wave-reduce, 1 atomic/wave ----
    double lq = (double)xnorm + chosen;
#pragma unroll
    for (int off = 32; off > 0; off >>= 1)
        lq += __shfl_down(lq, off, 64);
    if ((tid & 63) == 0)
        atomicAdd(out + VQ_TOTAL, (float)(lq * (1.0 / (double)VQ_TOTAL)));
}

extern "C" void kernel_launch(void* const* d_in, const int* in_sizes, int n_in,
                              void* d_out, int out_size, void* d_ws, size_t ws_size,
                              hipStream_t stream) {
    const float* in = (const float*)d_in[0];
    const float* w  = (const float*)d_in[1];
    float* out = (float*)d_out;

    hipMemsetAsync(out + VQ_TOTAL, 0, sizeof(float), stream);
    vq_main<<<VQ_NQ / 256, 256, 0, stream>>>(in, w, out);
}

// Round 5
// 197.411 us; speedup vs baseline: 2.0218x; 1.8960x over previous
//
#include <hip/hip_runtime.h>
#include <math.h>

// VectorQuantizer via MFMA: in [32,64,64,64] fp32 NCHW (C=D=64), w [512,64] fp32.
// Distances = ||w||^2 - 2 x.w via bf16 hi/lo split (4 MFMA products, err ~3e-4,
// same as fp32-accum) + fp64 re-rank of near-ties (tau gate, proven in R1-R4).
// R2/R4 post-mortem: fp32-VALU path is LDS-return-bus-bound at ~260 us (broadcast
// b128 writes per-lane copies). MFMA 16x16x32 with swizzled fragment tiles:
// MFMA ~16.5us / LDS ~17us / VALU ~11us per-CU, overlapping.
typedef short bf16x8 __attribute__((ext_vector_type(8)));
typedef float f32x4 __attribute__((ext_vector_type(4)));

#define VQ_D 64
#define VQ_K 512
#define VQ_NQ 131072
#define VQ_TOTAL 8388608
#define QB 64          // queries per block (4 waves x 16)
#define KP 128         // codes per LDS pass
#define NPASS 4

__device__ __forceinline__ ushort bf16_rne(float f) {
    uint u = __builtin_bit_cast(uint, f);
    u += 0x7fffu + ((u >> 16) & 1u);
    return (ushort)(u >> 16);
}
__device__ __forceinline__ float bf16_to_f(ushort h) {
    uint u = ((uint)h) << 16;
    return __builtin_bit_cast(float, u);
}

// ---- prep: w -> bf16 hi/lo, granule-swizzled rows, + fp32 norms (into d_ws) ----
// Row layout (256 B): [hi 64 bf16][lo 64 bf16]; 16-B granule g=d>>3 stored at
// phys p = (g ^ (k&7)) & 7  -> frag reads hit 8 distinct bank-quads (optimal).
__global__ __launch_bounds__(512) void vq_prep(const float* __restrict__ w,
                                               ushort* __restrict__ wbf,
                                               float* __restrict__ wn) {
    const int k = threadIdx.x;           // one block of 512 = one code per thread
    const float* row = w + k * VQ_D;
    ushort* orow = wbf + k * 128;
    double sd = 0.0;
    for (int d = 0; d < VQ_D; ++d) {
        float v = row[d];
        sd = fma((double)v, (double)v, sd);
        ushort h = bf16_rne(v);
        ushort l = bf16_rne(v - bf16_to_f(h));
        int p = ((d >> 3) ^ (k & 7)) & 7;
        orow[p * 8 + (d & 7)]      = h;
        orow[64 + p * 8 + (d & 7)] = l;
    }
    wn[k] = (float)sd;
}

__global__ __launch_bounds__(256, 2) void vq_main(const float* __restrict__ in,
                                                  const float* __restrict__ w,
                                                  const ushort* __restrict__ wbf,
                                                  const float* __restrict__ wng,
                                                  float* __restrict__ out) {
    __shared__ ushort x_lds[QB * 128];    // 16 KB: per query [hi64][lo64] swizzled
    __shared__ ushort w_lds[KP * 128];    // 32 KB: per code, same layout
    __shared__ float wn_lds[VQ_K];        // 2 KB
    __shared__ float xnorm_lds[QB];
    __shared__ float best_lds[QB], sec_lds[QB];
    __shared__ int   bi_lds[QB], si_lds[QB];

    const int tid  = threadIdx.x;
    const int lane = tid & 63;
    const int wid  = tid >> 6;          // wave id: queries wid*16..wid*16+15
    const int col  = lane & 15;         // MFMA col (code within tile / A-row query)
    const int quad = lane >> 4;         // MFMA quad (k-group; C rows quad*4+j)
    const int n0  = blockIdx.x * QB;
    const int b   = n0 >> 12;
    const int hw0 = n0 & 4095;
    const float* xg = in + (b << 18) + hw0;

    // ---- init + wn stage ----
    if (tid < QB) xnorm_lds[tid] = 0.f;
    wn_lds[tid]       = wng[tid];
    wn_lds[tid + 256] = wng[tid + 256];
    __syncthreads();

    // ---- x: coalesced global read, fp32->bf16 hi/lo, swizzled LDS write ----
    {
        float xn[4] = {0.f, 0.f, 0.f, 0.f};
        const int q0 = (tid & 15) * 4;
#pragma unroll
        for (int i = 0; i < 4; ++i) {
            const int d = (tid >> 4) + 16 * i;
            float4 v = *(const float4*)(xg + (d << 12) + q0);
            float vv[4] = {v.x, v.y, v.z, v.w};
#pragma unroll
            for (int e = 0; e < 4; ++e) {
                const int q = q0 + e;
                float f = vv[e];
                xn[e] = fmaf(f, f, xn[e]);
                ushort h = bf16_rne(f);
                ushort l = bf16_rne(f - bf16_to_f(h));
                int p = ((d >> 3) ^ (q & 7)) & 7;
                x_lds[q * 128 + p * 8 + (d & 7)]      = h;
                x_lds[q * 128 + 64 + p * 8 + (d & 7)] = l;
            }
        }
#pragma unroll
        for (int e = 0; e < 4; ++e) atomicAdd(&xnorm_lds[q0 + e], xn[e]);
    }
    __syncthreads();

    // ---- A fragments (once per wave; query row = qg+col, reused all tiles) ----
    // A[m=lane&15][k=quad*8+j]  (doc-verified layout for 16x16x32 bf16)
    const int arow = wid * 16 + col;
    const ushort* xr = x_lds + arow * 128;
    const int pa0 = ((0 + quad) ^ (arow & 7)) & 7;   // k-step 0: granule quad
    const int pa1 = ((4 + quad) ^ (arow & 7)) & 7;   // k-step 1: granule 4+quad
    const bf16x8 ah0 = *(const bf16x8*)(xr + pa0 * 8);
    const bf16x8 ah1 = *(const bf16x8*)(xr + pa1 * 8);
    const bf16x8 al0 = *(const bf16x8*)(xr + 64 + pa0 * 8);
    const bf16x8 al1 = *(const bf16x8*)(xr + 64 + pa1 * 8);

    float best[4], secnd[4];
    int bI[4], sI[4];
#pragma unroll
    for (int j = 0; j < 4; ++j) { best[j] = 3.4e38f; secnd[j] = 3.4e38f; bI[j] = 0; sI[j] = 0; }

    for (int pass = 0; pass < NPASS; ++pass) {
        if (pass) __syncthreads();
        // stage pre-swizzled w rows: straight 32 KB copy ((pass*128+c)&7 == c&7)
        {
            const uint4* src = (const uint4*)wbf + pass * 2048;
            uint4* dst = (uint4*)w_lds;
#pragma unroll
            for (int i = 0; i < 8; ++i) dst[tid + i * 256] = src[tid + i * 256];
        }
        __syncthreads();

#pragma unroll
        for (int t = 0; t < 8; ++t) {
            const int c = t * 16 + col;               // LDS code row (= B col n)
            const ushort* wr = w_lds + c * 128;
            const int p0 = ((0 + quad) ^ (c & 7)) & 7;
            const int p1 = ((4 + quad) ^ (c & 7)) & 7;
            const bf16x8 bh0 = *(const bf16x8*)(wr + p0 * 8);
            const bf16x8 bh1 = *(const bf16x8*)(wr + p1 * 8);
            const bf16x8 bl0 = *(const bf16x8*)(wr + 64 + p0 * 8);
            const bf16x8 bl1 = *(const bf16x8*)(wr + 64 + p1 * 8);
            f32x4 a0 = {0.f, 0.f, 0.f, 0.f}, a1 = {0.f, 0.f, 0.f, 0.f};
            a0 = __builtin_amdgcn_mfma_f32_16x16x32_bf16(ah0, bh0, a0, 0, 0, 0);
            a0 = __builtin_amdgcn_mfma_f32_16x16x32_bf16(ah1, bh1, a0, 0, 0, 0);
            a0 = __builtin_amdgcn_mfma_f32_16x16x32_bf16(ah0, bl0, a0, 0, 0, 0);
            a0 = __builtin_amdgcn_mfma_f32_16x16x32_bf16(ah1, bl1, a0, 0, 0, 0);
            a1 = __builtin_amdgcn_mfma_f32_16x16x32_bf16(al0, bh0, a1, 0, 0, 0);
            a1 = __builtin_amdgcn_mfma_f32_16x16x32_bf16(al1, bh1, a1, 0, 0, 0);
            a1 = __builtin_amdgcn_mfma_f32_16x16x32_bf16(al0, bl0, a1, 0, 0, 0);
            a1 = __builtin_amdgcn_mfma_f32_16x16x32_bf16(al1, bl1, a1, 0, 0, 0);

            const int kg = pass * KP + t * 16 + col;  // global code of this lane's col
            const float wnv = wn_lds[kg];
#pragma unroll
            for (int j = 0; j < 4; ++j) {             // C: row=quad*4+j (query), col (code)
                float dist = fmaf(-2.f, a0[j] + a1[j], wnv);
                bool lt  = dist < best[j];
                bool lt2 = (!lt) && (dist < secnd[j]);
                secnd[j] = lt ? best[j] : (lt2 ? dist : secnd[j]);
                sI[j]    = lt ? bI[j]   : (lt2 ? kg   : sI[j]);
                best[j]  = lt ? dist    : best[j];
                bI[j]    = lt ? kg      : bI[j];
            }
        }
    }

    // ---- merge across the 16 col-lanes (disjoint code sets, lex (dist,idx)) ----
#pragma unroll
    for (int off = 1; off < 16; off <<= 1) {
#pragma unroll
        for (int j = 0; j < 4; ++j) {
            float ob = __shfl_xor(best[j], off, 64);
            float os = __shfl_xor(secnd[j], off, 64);
            int   oi = __shfl_xor(bI[j], off, 64);
            int   oc = __shfl_xor(sI[j], off, 64);
            bool oWins = (ob < best[j]) || (ob == best[j] && oi < bI[j]);
            float nb  = oWins ? ob      : best[j];
            int   ni  = oWins ? oi      : bI[j];
            float c1  = oWins ? best[j] : ob;
            int   ci1 = oWins ? bI[j]   : oi;
            float c2  = oWins ? os      : secnd[j];
            int   ci2 = oWins ? oc      : sI[j];
            bool c1w = (c1 < c2) || (c1 == c2 && ci1 < ci2);
            secnd[j] = c1w ? c1 : c2;
            sI[j]    = c1w ? ci1 : ci2;
            best[j] = nb; bI[j] = ni;
        }
    }
    if (col == 0) {
#pragma unroll
        for (int j = 0; j < 4; ++j) {
            const int q = wid * 16 + quad * 4 + j;
            best_lds[q] = best[j]; sec_lds[q] = secnd[j];
            bi_lds[q] = bI[j];     si_lds[q] = sI[j];
        }
    }
    __syncthreads();

    // ---- epilogue: fp64 near-tie re-rank (x from global), loss partial ----
    if (tid < QB) {
        const int q = tid;
        float cb = best_lds[q], cs = sec_lds[q];
        int cbi = bi_lds[q], csi = si_lds[q];
        double chosen = (double)cb;
        if (cs - cb < 8e-3f) {
            const float* wb  = w + cbi * VQ_D;
            const float* ws2 = w + csi * VQ_D;
            const float* xqp = xg + q;
            double nb = 0.0, dotb = 0.0, ns = 0.0, dots = 0.0;
            for (int d = 0; d < VQ_D; ++d) {
                double xv = (double)xqp[d << 12];
                double wbv = (double)wb[d], wsv = (double)ws2[d];
                nb = fma(wbv, wbv, nb); dotb = fma(xv, wbv, dotb);
                ns = fma(wsv, wsv, ns); dots = fma(xv, wsv, dots);
            }
            double db = nb - 2.0 * dotb, ds = ns - 2.0 * dots;
            if (ds < db || (ds == db && csi < cbi)) { cbi = csi; chosen = ds; }
            else                                    { chosen = db; }
        }
        bi_lds[q] = cbi;
        double lq = (double)xnorm_lds[q] + chosen;   // ||x-e||^2
#pragma unroll
        for (int off = 32; off > 0; off >>= 1)
            lq += __shfl_down(lq, off, 64);
        if (tid == 0)
            atomicAdd(out + VQ_TOTAL, (float)(lq * (1.0 / (double)VQ_TOTAL)));
    }
    __syncthreads();

    // ---- cooperative quantized write: coalesced 64-dword rows per channel ----
    {
        const int q = tid & 63, sec = tid >> 6;      // sec covers d in [16*sec,16*sec+16)
        const float4* wrow = (const float4*)(w + bi_lds[q] * VQ_D) + sec * 4;
        float* op = out + (b << 18) + hw0 + q;
#pragma unroll
        for (int u = 0; u < 4; ++u) {
            float4 v = wrow[u];
            const int d = sec * 16 + 4 * u;
            op[(d + 0) << 12] = v.x;
            op[(d + 1) << 12] = v.y;
            op[(d + 2) << 12] = v.z;
            op[(d + 3) << 12] = v.w;
        }
    }
}

extern "C" void kernel_launch(void* const* d_in, const int* in_sizes, int n_in,
                              void* d_out, int out_size, void* d_ws, size_t ws_size,
                              hipStream_t stream) {
    const float* in = (const float*)d_in[0];
    const float* w  = (const float*)d_in[1];
    float* out = (float*)d_out;

    ushort* wbf = (ushort*)d_ws;                       // 512*128 ushort = 128 KB
    float*  wn  = (float*)((char*)d_ws + 131072);      // 512 floats

    hipMemsetAsync(out + VQ_TOTAL, 0, sizeof(float), stream);
    vq_prep<<<1, 512, 0, stream>>>(w, wbf, wn);
    vq_main<<<VQ_NQ / QB, 256, 0, stream>>>(in, w, wbf, wn, out);
}

// Round 6
// 140.983 us; speedup vs baseline: 2.8309x; 1.4002x over previous
//
#include <hip/hip_runtime.h>
#include <math.h>

// VectorQuantizer via MFMA: in [32,64,64,64] fp32 NCHW (C=D=64), w [512,64] fp32.
// R5 post-mortem: 87us outside vq_main (serial 1-block prep), 8e6 LDS bank
// conflicts (scattered ushort x-staging), 2.2 waves/SIMD. R6: W pre-swizzled
// into MFMA B-fragment order in d_ws -> K-loop reads B direct from global
// (coalesced, L2-hot 128 KB, no LDS, no barriers); 2 A-tiles/wave; 3-product
// hi/lo split (drop lo*lo, err <= 2e-4, tau=8e-3 covers); x-staging via
// b128 granule writes into 272B-padded rows (conflict-free); prep parallel.
typedef short bf16x8 __attribute__((ext_vector_type(8)));
typedef float f32x4 __attribute__((ext_vector_type(4)));

#define VQ_D 64
#define VQ_K 512
#define VQ_NQ 131072
#define VQ_TOTAL 8388608
#define QB 128           // queries per block (4 waves x 2 A-tiles x 16)
#define NT 32            // B-tiles (512 / 16)
#define XPITCH 136       // ushorts per x row: 128 data + 8 pad (272 B, bank-spread)

__device__ __forceinline__ ushort bf16_rne(float f) {
    uint u = __builtin_bit_cast(uint, f);
    u += 0x7fffu + ((u >> 16) & 1u);
    return (ushort)(u >> 16);
}
__device__ __forceinline__ float bf16_to_f(ushort h) {
    uint u = ((uint)h) << 16;
    return __builtin_bit_cast(float, u);
}

// ---- prep: w -> bf16 hi/lo in MFMA B-fragment order + fp32 norms ----
// wfrag layout: [tile t(32)][frag f(4: bh0,bh1,bl0,bl1)][lane(64)][8 ushort]
// lane = quad*16+col holds code (t*16+col), d in [kstep*32 + quad*8, +8).
__global__ __launch_bounds__(64) void vq_prep(const float* __restrict__ w,
                                              ushort* __restrict__ wfrag,
                                              float* __restrict__ wn) {
    const int k = blockIdx.x * 64 + threadIdx.x;   // one code per thread
    const float4* row = (const float4*)(w + k * VQ_D);
    const int t = k >> 4, col = k & 15;
    double sd = 0.0;
    for (int g = 0; g < 8; ++g) {                  // granule g: d in [g*8, g*8+8)
        float4 a = row[2 * g], b4 = row[2 * g + 1];
        float v[8] = {a.x, a.y, a.z, a.w, b4.x, b4.y, b4.z, b4.w};
        ushort hi[8], lo[8];
#pragma unroll
        for (int j = 0; j < 8; ++j) {
            sd = fma((double)v[j], (double)v[j], sd);
            hi[j] = bf16_rne(v[j]);
            lo[j] = bf16_rne(v[j] - bf16_to_f(hi[j]));
        }
        const int quad = g & 3, fh = g >> 2;       // kstep
        const int lane = quad * 16 + col;
        bf16x8* basez = (bf16x8*)wfrag + t * 256 + lane;
        *(basez + (fh)*64)     = *(bf16x8*)hi;     // bh{fh}
        *(basez + (2 + fh)*64) = *(bf16x8*)lo;     // bl{fh}
    }
    wn[k] = (float)sd;
}

__global__ __launch_bounds__(256, 3) void vq_main(const float* __restrict__ in,
                                                  const float* __restrict__ w,
                                                  const ushort* __restrict__ wfrag,
                                                  const float* __restrict__ wng,
                                                  float* __restrict__ out) {
    __shared__ ushort x_lds[QB * XPITCH];   // 34 KB, 272B rows: [hi 8x8][lo 8x8][pad]
    __shared__ float wn_lds[VQ_K];          // 2 KB
    __shared__ float xn_lds[2][QB];         // 1 KB partial query norms
    __shared__ float best_lds[QB], sec_lds[QB];
    __shared__ int   bi_lds[QB], si_lds[QB];

    const int tid  = threadIdx.x;
    const int lane = tid & 63;
    const int wid  = tid >> 6;
    const int col  = lane & 15;
    const int quad = lane >> 4;
    const int n0  = blockIdx.x * QB;
    const int b   = n0 >> 12;
    const int hw0 = n0 & 4095;
    const float* xg = in + (b << 18) + hw0;

    // ---- stage wn + x (granule-wise, conflict-free b128 writes) ----
    wn_lds[tid] = wng[tid];
    wn_lds[tid + 256] = wng[tid + 256];
    {
        const int q = tid & 127, gh = tid >> 7;    // gh: granules gh*4..gh*4+3
        const float* xq = xg + q;
        float xnp = 0.f;
#pragma unroll
        for (int i = 0; i < 4; ++i) {
            const int g = gh * 4 + i;
            float v[8];
            ushort hi[8], lo[8];
#pragma unroll
            for (int j = 0; j < 8; ++j) v[j] = xq[(g * 8 + j) << 12];  // coalesced over q
#pragma unroll
            for (int j = 0; j < 8; ++j) {
                xnp = fmaf(v[j], v[j], xnp);
                hi[j] = bf16_rne(v[j]);
                lo[j] = bf16_rne(v[j] - bf16_to_f(hi[j]));
            }
            *(bf16x8*)&x_lds[q * XPITCH + g * 8]      = *(bf16x8*)hi;
            *(bf16x8*)&x_lds[q * XPITCH + 64 + g * 8] = *(bf16x8*)lo;
        }
        xn_lds[gh][q] = xnp;
    }
    __syncthreads();

    // ---- A fragments: 2 tiles (32 queries) per wave, register-resident ----
    const int arow0 = wid * 32 + col;
    bf16x8 ah0[2], ah1[2], al0[2], al1[2];
#pragma unroll
    for (int T = 0; T < 2; ++T) {
        const ushort* xr = x_lds + (arow0 + T * 16) * XPITCH;
        ah0[T] = *(const bf16x8*)(xr + quad * 8);
        ah1[T] = *(const bf16x8*)(xr + 32 + quad * 8);
        al0[T] = *(const bf16x8*)(xr + 64 + quad * 8);
        al1[T] = *(const bf16x8*)(xr + 96 + quad * 8);
    }

    float best[8], secnd[8];
    int bI[8], sI[8];
#pragma unroll
    for (int r = 0; r < 8; ++r) { best[r] = 3.4e38f; secnd[r] = 3.4e38f; bI[r] = 0; sI[r] = 0; }

    // ---- K-loop: B frags straight from global (L2-hot), 1-tile prefetch ----
    const bf16x8* wf = (const bf16x8*)wfrag + lane;
    bf16x8 bh0 = wf[0], bh1 = wf[64], bl0 = wf[128], bl1 = wf[192];

    for (int t = 0; t < NT; ++t) {
        bf16x8 nh0, nh1, nl0, nl1;
        if (t + 1 < NT) {
            const bf16x8* nx = wf + (t + 1) * 256;
            nh0 = nx[0]; nh1 = nx[64]; nl0 = nx[128]; nl1 = nx[192];
        }
        const float wnv = wn_lds[t * 16 + col];
#pragma unroll
        for (int T = 0; T < 2; ++T) {
            f32x4 accP = {0.f, 0.f, 0.f, 0.f}, accQ = {0.f, 0.f, 0.f, 0.f};
            accP = __builtin_amdgcn_mfma_f32_16x16x32_bf16(ah0[T], bh0, accP, 0, 0, 0);
            accP = __builtin_amdgcn_mfma_f32_16x16x32_bf16(ah1[T], bh1, accP, 0, 0, 0);
            accQ = __builtin_amdgcn_mfma_f32_16x16x32_bf16(ah0[T], bl0, accQ, 0, 0, 0);
            accQ = __builtin_amdgcn_mfma_f32_16x16x32_bf16(ah1[T], bl1, accQ, 0, 0, 0);
            accQ = __builtin_amdgcn_mfma_f32_16x16x32_bf16(al0[T], bh0, accQ, 0, 0, 0);
            accQ = __builtin_amdgcn_mfma_f32_16x16x32_bf16(al1[T], bh1, accQ, 0, 0, 0);
            const int kg = t * 16 + col;
#pragma unroll
            for (int j = 0; j < 4; ++j) {          // C: row(query)=quad*4+j, col=code
                float dist = fmaf(-2.f, accP[j] + accQ[j], wnv);
                const int r = T * 4 + j;
                bool lt  = dist < best[r];
                bool lt2 = (!lt) && (dist < secnd[r]);
                secnd[r] = lt ? best[r] : (lt2 ? dist : secnd[r]);
                sI[r]    = lt ? bI[r]   : (lt2 ? kg   : sI[r]);
                best[r]  = lt ? dist    : best[r];
                bI[r]    = lt ? kg      : bI[r];
            }
        }
        bh0 = nh0; bh1 = nh1; bl0 = nl0; bl1 = nl1;
    }

    // ---- merge across 16 col-lanes (disjoint code sets, lex (dist,idx)) ----
#pragma unroll
    for (int off = 1; off < 16; off <<= 1) {
#pragma unroll
        for (int r = 0; r < 8; ++r) {
            float ob = __shfl_xor(best[r], off, 64);
            float os = __shfl_xor(secnd[r], off, 64);
            int   oi = __shfl_xor(bI[r], off, 64);
            int   oc = __shfl_xor(sI[r], off, 64);
            bool oWins = (ob < best[r]) || (ob == best[r] && oi < bI[r]);
            float nb  = oWins ? ob      : best[r];
            int   ni  = oWins ? oi      : bI[r];
            float c1  = oWins ? best[r] : ob;
            int   ci1 = oWins ? bI[r]   : oi;
            float c2  = oWins ? os      : secnd[r];
            int   ci2 = oWins ? oc      : sI[r];
            bool c1w = (c1 < c2) || (c1 == c2 && ci1 < ci2);
            secnd[r] = c1w ? c1 : c2;
            sI[r]    = c1w ? ci1 : ci2;
            best[r] = nb; bI[r] = ni;
        }
    }
    if (col == 0) {
#pragma unroll
        for (int r = 0; r < 8; ++r) {
            const int q = wid * 32 + (r >> 2) * 16 + quad * 4 + (r & 3);
            best_lds[q] = best[r]; sec_lds[q] = secnd[r];
            bi_lds[q] = bI[r];     si_lds[q] = sI[r];
        }
    }
    __syncthreads();

    // ---- epilogue: fp64 near-tie re-rank + loss (128 threads, 1 query each) ----
    if (tid < QB) {
        const int q = tid;
        float cb = best_lds[q], cs = sec_lds[q];
        int cbi = bi_lds[q], csi = si_lds[q];
        double chosen = (double)cb;
        if (cs - cb < 8e-3f) {
            const float* wb  = w + cbi * VQ_D;
            const float* ws2 = w + csi * VQ_D;
            const float* xqp = xg + q;
            double nb = 0.0, dotb = 0.0, ns = 0.0, dots = 0.0;
            for (int d = 0; d < VQ_D; ++d) {
                double xv = (double)xqp[d << 12];
                double wbv = (double)wb[d], wsv = (double)ws2[d];
                nb = fma(wbv, wbv, nb); dotb = fma(xv, wbv, dotb);
                ns = fma(wsv, wsv, ns); dots = fma(xv, wsv, dots);
            }
            double db = nb - 2.0 * dotb, ds = ns - 2.0 * dots;
            if (ds < db || (ds == db && csi < cbi)) { cbi = csi; chosen = ds; }
            else                                    { chosen = db; }
        }
        bi_lds[q] = cbi;
        double lq = (double)(xn_lds[0][q] + xn_lds[1][q]) + chosen;  // ||x-e||^2
#pragma unroll
        for (int off = 32; off > 0; off >>= 1)
            lq += __shfl_down(lq, off, 64);
        if ((tid & 63) == 0)
            atomicAdd(out + VQ_TOTAL, (float)(lq * (1.0 / (double)VQ_TOTAL)));
    }
    __syncthreads();

    // ---- cooperative quantized write: coalesced 128-dword rows per channel ----
    {
        const int q = tid & 127, half = tid >> 7;  // half covers d in [32*half, +32)
        const float4* wrow = (const float4*)(w + bi_lds[q] * VQ_D) + half * 8;
        float* op = out + (b << 18) + hw0 + q;
#pragma unroll
        for (int u = 0; u < 8; ++u) {
            float4 v = wrow[u];
            const int d = half * 32 + 4 * u;
            op[(d + 0) << 12] = v.x;
            op[(d + 1) << 12] = v.y;
            op[(d + 2) << 12] = v.z;
            op[(d + 3) << 12] = v.w;
        }
    }
}

extern "C" void kernel_launch(void* const* d_in, const int* in_sizes, int n_in,
                              void* d_out, int out_size, void* d_ws, size_t ws_size,
                              hipStream_t stream) {
    const float* in = (const float*)d_in[0];
    const float* w  = (const float*)d_in[1];
    float* out = (float*)d_out;

    ushort* wfrag = (ushort*)d_ws;                    // 512*128 ushort = 128 KB
    float*  wn    = (float*)((char*)d_ws + 131072);   // 512 floats

    hipMemsetAsync(out + VQ_TOTAL, 0, sizeof(float), stream);
    vq_prep<<<8, 64, 0, stream>>>(w, wfrag, wn);
    vq_main<<<VQ_NQ / QB, 256, 0, stream>>>(in, w, wfrag, wn, out);
}